// Round 10
// baseline (145.996 us; speedup 1.0000x reference)
//
#include <hip/hip_runtime.h>
#include <hip/hip_bf16.h>

// GraphSAGE fused kernels for MI355X (gfx950).
// N=768, NODE_IN=64, EDGE_IN=32, H=128, ROUNDS=2.
//
// Round 10: TLP restructure. k_big time was invariant (~55us) across R5/R8/R9
// while occupancy tracked total regs/wave (R4:64regs->31%, R9:~180->15%,
// R8:~230->9.5%) -> latency-bound with ~2 waves/SIMD. Now 512-thread blocks,
// 8 waves = 2(wr) x 4(wc); each wave 16 rows x 32 cols -> ~110 total regs
// (bwe 8 + bwa 32 + ae 16 + acc 8 + C1 8 + prefetch 8 + addr) -> 4 waves/SIMD,
// LDS ~18.5KB -> 2 blocks/CU -> 16 waves/CU cap. Pruning, sentinel sp row,
// 2-barrier dbuf pipeline, plain __launch_bounds__ kept.

typedef __bf16 bf16x8 __attribute__((ext_vector_type(8)));
typedef float f32x4 __attribute__((ext_vector_type(4)));

#define NN 768

static __device__ __forceinline__ unsigned short to_bf16u(float x) {
    return __builtin_bit_cast(unsigned short, (__bf16)x);
}

// ---------------------------------------------------------------- fused prep
// blocks 0..575   : adj transpose (32x32 tiles)
// blocks 576..655 : weight transposes We->WeT, Wa[H:]->Wa2T (bf16 k-minor)
// blocks 656..1039: h0 = relu(nf@Wn+bn) and sp = h0@Wa[:H]+ba (plain layout)
// block  1040     : sp sentinel row 768 = -1e30 (padded-slot C-init)
__global__ __launch_bounds__(256) void k_prep(
                       const float* __restrict__ adj, float* __restrict__ adjT,
                       const float* __restrict__ We, const float* __restrict__ Wa,
                       unsigned short* __restrict__ WeT, unsigned short* __restrict__ Wa2T,
                       const float* __restrict__ nf, const float* __restrict__ Wn,
                       const float* __restrict__ bn, const float* __restrict__ ba,
                       float* __restrict__ h, float* __restrict__ sp) {
    const int b = blockIdx.x, tid = threadIdx.x;
    if (b < 576) {
        __shared__ float tile[32][33];
        int bx = b % 24, by = b / 24;
        int tx = tid & 31, ty = tid >> 5;  // 32 x 8
#pragma unroll
        for (int yy = 0; yy < 32; yy += 8)
            tile[ty + yy][tx] = adj[(size_t)(by * 32 + ty + yy) * NN + bx * 32 + tx];
        __syncthreads();
#pragma unroll
        for (int yy = 0; yy < 32; yy += 8)
            adjT[(size_t)(bx * 32 + ty + yy) * NN + by * 32 + tx] = tile[tx][ty + yy];
    } else if (b < 656) {
        int g = (b - 576) * 256 + tid;
        if (g < 128 * 32) {
            int c = g >> 5, f = g & 31;
            WeT[g] = to_bf16u(We[f * 128 + c]);
        } else {
            int g2 = g - 128 * 32;
            int c = g2 >> 7, k = g2 & 127;
            Wa2T[g2] = to_bf16u(Wa[(128 + k) * 128 + c]);
        }
    } else if (b < 1040) {
        __shared__ float nf_l[2][64];
        __shared__ float h_l[2][128];
        int row = tid >> 7, t = tid & 127;
        int i = (b - 656) * 2 + row;
        if (t < 64) nf_l[row][t] = nf[i * 64 + t];
        __syncthreads();
        float acc = bn[t];
#pragma unroll 8
        for (int f = 0; f < 64; ++f) acc += nf_l[row][f] * Wn[f * 128 + t];
        acc = fmaxf(acc, 0.f);
        h[i * 128 + t] = acc;
        h_l[row][t] = acc;
        __syncthreads();
        float spv = ba[t];
#pragma unroll 8
        for (int f = 0; f < 128; ++f) spv += h_l[row][f] * Wa[f * 128 + t];
        sp[i * 128 + t] = spv;
    } else {
        if (tid < 128) sp[(size_t)NN * 128 + tid] = -1e30f;
    }
}

// ---------------------------------------------------------------- the big fused kernel
// Block = receiver j. 8 waves in 2x4: wr = row-group (16 of 32 chunk rows),
// wc = col-quarter (32 of 128 cols). Chunk = 32 compacted senders.
__global__ __launch_bounds__(512) void k_big(
    const float* __restrict__ ef, const float* __restrict__ adjT,
    const float* __restrict__ sp, const unsigned short* __restrict__ WeT,
    const unsigned short* __restrict__ Wa2T, const float* __restrict__ be,
    float* __restrict__ agg) {
    __shared__ __align__(16) unsigned short e_lds[2][2][16 * 128]; // dbuf x wr, 16KB
    __shared__ unsigned short idx_lds[NN];                         // compacted senders
    __shared__ float be_lds[128];
    __shared__ int s_cnt;
    __shared__ float s_invdeg;

    const int tid  = threadIdx.x;
    const int j    = blockIdx.x;
    const int lane = tid & 63;
    const int wv   = tid >> 6;     // 0..7
    const int wr   = wv >> 2;      // 0..1
    const int wc   = wv & 3;       // 0..3
    const int lg   = lane >> 4;
    const int lr   = lane & 15;

    if (tid < 128) be_lds[tid] = be[tid];

    // ---- B-frags in registers: We (2 col-tiles) + Wa2 (2 col-tiles x 4 k-tiles)
    bf16x8 bwe[2];
    bf16x8 bwa[2][4];
#pragma unroll
    for (int t = 0; t < 2; ++t) {
        const int col = 32 * wc + 16 * t + lr;
        bwe[t] = *reinterpret_cast<const bf16x8*>(WeT + col * 32 + 8 * lg);
#pragma unroll
        for (int s = 0; s < 4; ++s)
            bwa[t][s] = *reinterpret_cast<const bf16x8*>(Wa2T + col * 128 + 32 * s + 8 * lg);
    }

    // ---- wave 0: ballot-compaction of adj column j
    if (wv == 0) {
        int cnt = 0;
#pragma unroll
        for (int b = 0; b < 12; ++b) {
            float v = adjT[(size_t)j * NN + b * 64 + lane];
            unsigned long long m = __ballot(v != 0.0f);
            if (v != 0.0f) {
                int pos = cnt + __popcll(m & ((1ULL << lane) - 1ULL));
                idx_lds[pos] = (unsigned short)(b * 64 + lane);
            }
            cnt += (int)__popcll(m);
        }
        if (lane == 0) {
            s_cnt = cnt;
            s_invdeg = 1.0f / fmaxf((float)cnt, 1.0f);
        }
    }
    __syncthreads();

    const int cnt = s_cnt;
    const int Kc = (cnt + 31) >> 5;   // chunks of 32 slots (16 per row-group)

    float aggp[2] = {0.f, 0.f};

    // load this wave's GEMM1 ef row for chunk m (row-group wr, row lr)
    auto load_ef = [&](int m, float4& x0, float4& x1) {
        int s = 32 * m + 16 * wr + lr;
        int r = (s < cnt) ? (int)idx_lds[s] : 0;
        const float* p = ef + ((size_t)r * NN + j) * 32 + 8 * lg;
        x0 = *reinterpret_cast<const float4*>(p);
        x1 = *reinterpret_cast<const float4*>(p + 4);
    };
    // GEMM1: E(16x32 this wave) = relu(EF @ We + be) -> swizzled e_lds[buf][wr]
    auto gemm1 = [&](const float4& x0, const float4& x1, int buf) {
        bf16x8 a;
        a[0] = (__bf16)x0.x; a[1] = (__bf16)x0.y; a[2] = (__bf16)x0.z; a[3] = (__bf16)x0.w;
        a[4] = (__bf16)x1.x; a[5] = (__bf16)x1.y; a[6] = (__bf16)x1.z; a[7] = (__bf16)x1.w;
#pragma unroll
        for (int t = 0; t < 2; ++t) {
            const int col = 32 * wc + 16 * t + lr;
            float bb = be_lds[col];
            f32x4 c;
            c[0] = bb; c[1] = bb; c[2] = bb; c[3] = bb;
            f32x4 C1 = __builtin_amdgcn_mfma_f32_16x16x32_bf16(a, bwe[t], c, 0, 0, 0);
#pragma unroll
            for (int r = 0; r < 4; ++r) {
                int row = 4 * lg + r;
                int idx = (row * 128 + col) ^ ((row & 7) << 3);
                e_lds[buf][wr][idx] = to_bf16u(fmaxf(C1[r], 0.f));
            }
        }
    };

    float4 c0, c1;
    if (Kc > 0) {
        load_ef(0, c0, c1);
        gemm1(c0, c1, 0);
        if (Kc > 1) load_ef(1, c0, c1);
    }
    __syncthreads();   // E[0] ready

    for (int n = 0; n < Kc; ++n) {
        const int b = n & 1;
        float4 p0, p1;
        if (n + 2 < Kc) load_ef(n + 2, p0, p1);
        if (n + 1 < Kc) gemm1(c0, c1, b ^ 1);

        // ---- GEMM2 on chunk n: A-frags from e_lds[b][wr] (full K=128)
        bf16x8 ae[4];
#pragma unroll
        for (int s = 0; s < 4; ++s) {
            int idx = (lr * 128 + 32 * s + 8 * lg) ^ ((lr & 7) << 3);
            ae[s] = *reinterpret_cast<const bf16x8*>(&e_lds[b][wr][idx]);
        }
        int srow[4];
#pragma unroll
        for (int r = 0; r < 4; ++r) {
            int s = 32 * n + 16 * wr + 4 * lg + r;
            srow[r] = (s < cnt) ? (int)idx_lds[s] : NN;   // sentinel row -> relu kills
        }
#pragma unroll
        for (int t = 0; t < 2; ++t) {
            const int col = 32 * wc + 16 * t + lr;
            f32x4 acc;
#pragma unroll
            for (int r = 0; r < 4; ++r)
                acc[r] = sp[(size_t)srow[r] * 128 + col];
#pragma unroll
            for (int s = 0; s < 4; ++s)
                acc = __builtin_amdgcn_mfma_f32_16x16x32_bf16(ae[s], bwa[t][s], acc, 0, 0, 0);
#pragma unroll
            for (int r = 0; r < 4; ++r)
                aggp[t] += fmaxf(acc[r], 0.f);
        }

        if (n + 2 < Kc) { c0 = p0; c1 = p1; }
        __syncthreads();   // E[b^1] writes + E[b] reads complete
    }

    // ---- reduce: shfl over lg groups, per-wave partials into LDS, combine wr halves
    float* red = reinterpret_cast<float*>(&e_lds[0][0][0]);  // [8][32]
#pragma unroll
    for (int t = 0; t < 2; ++t) {
        float v = aggp[t];
        v += __shfl_xor(v, 16);
        v += __shfl_xor(v, 32);
        if (lane < 16) red[wv * 32 + 16 * t + lane] = v;
    }
    __syncthreads();
    if (tid < 128) {
        int wcol = tid >> 5, c32 = tid & 31;
        agg[(size_t)j * 128 + tid] =
            (red[wcol * 32 + c32] + red[(4 + wcol) * 32 + c32]) * s_invdeg;
    }
}

// ---------------------------------------------------------------- update (+ next-round sp, or final out)
template <int LAST>
__global__ __launch_bounds__(256) void k_upd(
                      const float* __restrict__ h_in, const float* __restrict__ agg,
                      const float* __restrict__ Wu, const float* __restrict__ bu,
                      const float* __restrict__ Wa, const float* __restrict__ ba,
                      float* __restrict__ h_out, float* __restrict__ sp,
                      float* __restrict__ out) {
    __shared__ float buf[2][256];
    __shared__ float hn[2][128];
    const int tid = threadIdx.x;
    const int row = tid >> 7, t = tid & 127;
    const int i = blockIdx.x * 2 + row;
    buf[row][t] = h_in[i * 128 + t];
    buf[row][128 + t] = agg[i * 128 + t];
    __syncthreads();
    float acc = bu[t];
#pragma unroll 8
    for (int f = 0; f < 256; ++f) acc += buf[row][f] * Wu[f * 128 + t];
    acc = fmaxf(acc, 0.f);
    if (LAST) {
        out[i * 128 + t] = acc;
    } else {
        h_out[i * 128 + t] = acc;
        hn[row][t] = acc;
        __syncthreads();
        float spv = ba[t];
#pragma unroll 8
        for (int f = 0; f < 128; ++f) spv += hn[row][f] * Wa[f * 128 + t];
        sp[i * 128 + t] = spv;
    }
}

// ---------------------------------------------------------------- graph embedding (reads h from out)
__global__ __launch_bounds__(64) void k_gemb(const float* __restrict__ out_h, float* __restrict__ out) {
    int c = blockIdx.x, l = threadIdx.x;
    float acc = 0.f;
    for (int i = l; i < NN; i += 64) acc += out_h[(size_t)i * 128 + c];
#pragma unroll
    for (int off = 32; off; off >>= 1) acc += __shfl_down(acc, off);
    if (l == 0) out[NN * 128 + c] = acc * (1.0f / 768.0f);
}

extern "C" void kernel_launch(void* const* d_in, const int* in_sizes, int n_in,
                              void* d_out, int out_size, void* d_ws, size_t ws_size,
                              hipStream_t stream) {
    const float* nf  = (const float*)d_in[0];
    const float* ef  = (const float*)d_in[1];
    const float* adj = (const float*)d_in[2];
    const float* Wn  = (const float*)d_in[3];
    const float* bn  = (const float*)d_in[4];
    const float* We  = (const float*)d_in[5];
    const float* be  = (const float*)d_in[6];
    const float* Wa  = (const float*)d_in[7];
    const float* ba  = (const float*)d_in[8];
    const float* Wu  = (const float*)d_in[9];
    const float* bu  = (const float*)d_in[10];
    float* out = (float*)d_out;

    // workspace carve-up (floats): h | agg | sp(+sentinel row) | adjT | WeT | Wa2T
    float* h_buf = (float*)d_ws;
    float* agg   = h_buf + NN * 128;
    float* sp    = agg + NN * 128;
    float* adjT  = sp + (NN + 1) * 128;
    unsigned short* WeT  = (unsigned short*)(adjT + NN * NN);
    unsigned short* Wa2T = WeT + 128 * 32;

    k_prep<<<1041, 256, 0, stream>>>(adj, adjT, We, Wa, WeT, Wa2T, nf, Wn, bn, ba, h_buf, sp);

    k_big<<<NN, 512, 0, stream>>>(ef, adjT, sp, WeT, Wa2T, be, agg);
    k_upd<0><<<NN / 2, 256, 0, stream>>>(h_buf, agg, Wu, bu, Wa, ba, h_buf, sp, out);
    k_big<<<NN, 512, 0, stream>>>(ef, adjT, sp, WeT, Wa2T, be, agg);
    k_upd<1><<<NN / 2, 256, 0, stream>>>(h_buf, agg, Wu, bu, Wa, ba, h_buf, sp, out);

    k_gemb<<<128, 64, 0, stream>>>(out, out);
}

// Round 11
// 140.018 us; speedup vs baseline: 1.0427x; 1.0427x over previous
//
#include <hip/hip_runtime.h>
#include <hip/hip_bf16.h>

// GraphSAGE fused kernels for MI355X (gfx950).
// N=768, NODE_IN=64, EDGE_IN=32, H=128, ROUNDS=2.
//
// Round 11: the ~55us k_big invariant across R5-R10 tracked FETCH/400GB/s
// exactly -> scattered 128B reads across the 75MB ef tensor are DRAM-row-
// activation bound (R4's contiguous spill traffic ran 2.3-3TB/s on the same
// chip). Fix: one-time LDS-tiled transpose ef[i][j][f] fp32 -> efT[j][i][f]
// bf16 (coalesced 1KB reads / 2KB writes), so each block j gathers within a
// 48KB contiguous slab (cache-friendly) at half the bytes, and GEMM1's A-frag
// becomes a direct bf16x8 load (no cvt). ws_size guard falls back to the R10
// path if the 41.4MB layout doesn't fit.

typedef __bf16 bf16x8 __attribute__((ext_vector_type(8)));
typedef float f32x4 __attribute__((ext_vector_type(4)));

#define NN 768

static __device__ __forceinline__ unsigned short to_bf16u(float x) {
    return __builtin_bit_cast(unsigned short, (__bf16)x);
}

// ---------------------------------------------------------------- fused prep
__global__ __launch_bounds__(256) void k_prep(
                       const float* __restrict__ adj, float* __restrict__ adjT,
                       const float* __restrict__ We, const float* __restrict__ Wa,
                       unsigned short* __restrict__ WeT, unsigned short* __restrict__ Wa2T,
                       const float* __restrict__ nf, const float* __restrict__ Wn,
                       const float* __restrict__ bn, const float* __restrict__ ba,
                       float* __restrict__ h, float* __restrict__ sp) {
    const int b = blockIdx.x, tid = threadIdx.x;
    if (b < 576) {
        __shared__ float tile[32][33];
        int bx = b % 24, by = b / 24;
        int tx = tid & 31, ty = tid >> 5;  // 32 x 8
#pragma unroll
        for (int yy = 0; yy < 32; yy += 8)
            tile[ty + yy][tx] = adj[(size_t)(by * 32 + ty + yy) * NN + bx * 32 + tx];
        __syncthreads();
#pragma unroll
        for (int yy = 0; yy < 32; yy += 8)
            adjT[(size_t)(bx * 32 + ty + yy) * NN + by * 32 + tx] = tile[tx][ty + yy];
    } else if (b < 656) {
        int g = (b - 576) * 256 + tid;
        if (g < 128 * 32) {
            int c = g >> 5, f = g & 31;
            WeT[g] = to_bf16u(We[f * 128 + c]);
        } else {
            int g2 = g - 128 * 32;
            int c = g2 >> 7, k = g2 & 127;
            Wa2T[g2] = to_bf16u(Wa[(128 + k) * 128 + c]);
        }
    } else if (b < 1040) {
        __shared__ float nf_l[2][64];
        __shared__ float h_l[2][128];
        int row = tid >> 7, t = tid & 127;
        int i = (b - 656) * 2 + row;
        if (t < 64) nf_l[row][t] = nf[i * 64 + t];
        __syncthreads();
        float acc = bn[t];
#pragma unroll 8
        for (int f = 0; f < 64; ++f) acc += nf_l[row][f] * Wn[f * 128 + t];
        acc = fmaxf(acc, 0.f);
        h[i * 128 + t] = acc;
        h_l[row][t] = acc;
        __syncthreads();
        float spv = ba[t];
#pragma unroll 8
        for (int f = 0; f < 128; ++f) spv += h_l[row][f] * Wa[f * 128 + t];
        sp[i * 128 + t] = spv;
    } else {
        if (tid < 128) sp[(size_t)NN * 128 + tid] = -1e30f;
    }
}

// ---------------------------------------------------------------- ef transpose+convert
// ef[i][j][f] fp32 -> efT[j][i][f] bf16. Tile: 32 i x 8 j. Coalesced 1KB
// global reads, 16B/lane coalesced writes (2KB runs per (j, i-block)).
__global__ __launch_bounds__(256) void k_eft(const float* __restrict__ ef,
                                             unsigned short* __restrict__ efT) {
    __shared__ unsigned short tile[8 * 1288 + 8];  // plane stride 1288, row stride 40
    const int b = blockIdx.x, t = threadIdx.x;
    const int i0 = (b % 24) * 32, j0 = (b / 24) * 8;
    {
        const int jj = t >> 5, ff = t & 31;
#pragma unroll 4
        for (int i = 0; i < 32; ++i) {
            float v = ef[((size_t)(i0 + i) * NN + j0 + jj) * 32 + ff];
            tile[jj * 1288 + i * 40 + ff] = to_bf16u(v);
        }
    }
    __syncthreads();
    const int tp = t & 31, j = t >> 5;
    unsigned short* dst = efT + ((size_t)(j0 + j) * NN + i0) * 32;
#pragma unroll
    for (int v = 0; v < 4; ++v) {
        int flat = v * 256 + tp * 8;   // consecutive lanes -> consecutive 16B
        int i = flat >> 5, f = flat & 31;
        bf16x8 val = *reinterpret_cast<const bf16x8*>(&tile[j * 1288 + i * 40 + f]);
        *reinterpret_cast<bf16x8*>(dst + flat) = val;
    }
}

// ---------------------------------------------------------------- k_big (efT bf16 path)
// Block = receiver j. 8 waves in 2x4 (wr x wc). Chunk = 32 compacted senders.
__global__ __launch_bounds__(512) void k_big_t(
    const unsigned short* __restrict__ efT, const float* __restrict__ adjT,
    const float* __restrict__ sp, const unsigned short* __restrict__ WeT,
    const unsigned short* __restrict__ Wa2T, const float* __restrict__ be,
    float* __restrict__ agg) {
    __shared__ __align__(16) unsigned short e_lds[2][2][16 * 128];
    __shared__ unsigned short idx_lds[NN];
    __shared__ float be_lds[128];
    __shared__ int s_cnt;
    __shared__ float s_invdeg;

    const int tid  = threadIdx.x;
    const int j    = blockIdx.x;
    const int lane = tid & 63;
    const int wv   = tid >> 6;
    const int wr   = wv >> 2;
    const int wc   = wv & 3;
    const int lg   = lane >> 4;
    const int lr   = lane & 15;

    if (tid < 128) be_lds[tid] = be[tid];

    bf16x8 bwe[2];
    bf16x8 bwa[2][4];
#pragma unroll
    for (int t = 0; t < 2; ++t) {
        const int col = 32 * wc + 16 * t + lr;
        bwe[t] = *reinterpret_cast<const bf16x8*>(WeT + col * 32 + 8 * lg);
#pragma unroll
        for (int s = 0; s < 4; ++s)
            bwa[t][s] = *reinterpret_cast<const bf16x8*>(Wa2T + col * 128 + 32 * s + 8 * lg);
    }

    if (wv == 0) {
        int cnt = 0;
#pragma unroll
        for (int b = 0; b < 12; ++b) {
            float v = adjT[(size_t)j * NN + b * 64 + lane];
            unsigned long long m = __ballot(v != 0.0f);
            if (v != 0.0f) {
                int pos = cnt + __popcll(m & ((1ULL << lane) - 1ULL));
                idx_lds[pos] = (unsigned short)(b * 64 + lane);
            }
            cnt += (int)__popcll(m);
        }
        if (lane == 0) {
            s_cnt = cnt;
            s_invdeg = 1.0f / fmaxf((float)cnt, 1.0f);
        }
    }
    __syncthreads();

    const int cnt = s_cnt;
    const int Kc = (cnt + 31) >> 5;

    float aggp[2] = {0.f, 0.f};

    // gather A-row from the contiguous 48KB efT[j] slab (bf16 direct)
    auto load_ef = [&](int m, bf16x8& x) {
        int s = 32 * m + 16 * wr + lr;
        int r = (s < cnt) ? (int)idx_lds[s] : 0;
        x = *reinterpret_cast<const bf16x8*>(efT + ((size_t)j * NN + r) * 32 + 8 * lg);
    };
    auto gemm1 = [&](bf16x8 a, int buf) {
#pragma unroll
        for (int t = 0; t < 2; ++t) {
            const int col = 32 * wc + 16 * t + lr;
            float bb = be_lds[col];
            f32x4 c;
            c[0] = bb; c[1] = bb; c[2] = bb; c[3] = bb;
            f32x4 C1 = __builtin_amdgcn_mfma_f32_16x16x32_bf16(a, bwe[t], c, 0, 0, 0);
#pragma unroll
            for (int r = 0; r < 4; ++r) {
                int row = 4 * lg + r;
                int idx = (row * 128 + col) ^ ((row & 7) << 3);
                e_lds[buf][wr][idx] = to_bf16u(fmaxf(C1[r], 0.f));
            }
        }
    };

    bf16x8 cA;
    if (Kc > 0) {
        load_ef(0, cA);
        gemm1(cA, 0);
        if (Kc > 1) load_ef(1, cA);
    }
    __syncthreads();

    for (int n = 0; n < Kc; ++n) {
        const int b = n & 1;
        bf16x8 pA;
        if (n + 2 < Kc) load_ef(n + 2, pA);
        if (n + 1 < Kc) gemm1(cA, b ^ 1);

        bf16x8 ae[4];
#pragma unroll
        for (int s = 0; s < 4; ++s) {
            int idx = (lr * 128 + 32 * s + 8 * lg) ^ ((lr & 7) << 3);
            ae[s] = *reinterpret_cast<const bf16x8*>(&e_lds[b][wr][idx]);
        }
        int srow[4];
#pragma unroll
        for (int r = 0; r < 4; ++r) {
            int s = 32 * n + 16 * wr + 4 * lg + r;
            srow[r] = (s < cnt) ? (int)idx_lds[s] : NN;
        }
#pragma unroll
        for (int t = 0; t < 2; ++t) {
            const int col = 32 * wc + 16 * t + lr;
            f32x4 acc;
#pragma unroll
            for (int r = 0; r < 4; ++r)
                acc[r] = sp[(size_t)srow[r] * 128 + col];
#pragma unroll
            for (int s = 0; s < 4; ++s)
                acc = __builtin_amdgcn_mfma_f32_16x16x32_bf16(ae[s], bwa[t][s], acc, 0, 0, 0);
#pragma unroll
            for (int r = 0; r < 4; ++r)
                aggp[t] += fmaxf(acc[r], 0.f);
        }

        if (n + 2 < Kc) cA = pA;
        __syncthreads();
    }

    float* red = reinterpret_cast<float*>(&e_lds[0][0][0]);  // [8][32]
#pragma unroll
    for (int t = 0; t < 2; ++t) {
        float v = aggp[t];
        v += __shfl_xor(v, 16);
        v += __shfl_xor(v, 32);
        if (lane < 16) red[wv * 32 + 16 * t + lane] = v;
    }
    __syncthreads();
    if (tid < 128) {
        int wcol = tid >> 5, c32 = tid & 31;
        agg[(size_t)j * 128 + tid] =
            (red[wcol * 32 + c32] + red[(4 + wcol) * 32 + c32]) * s_invdeg;
    }
}

// ---------------------------------------------------------------- k_big (R10 fp32 fallback)
__global__ __launch_bounds__(512) void k_big(
    const float* __restrict__ ef, const float* __restrict__ adjT,
    const float* __restrict__ sp, const unsigned short* __restrict__ WeT,
    const unsigned short* __restrict__ Wa2T, const float* __restrict__ be,
    float* __restrict__ agg) {
    __shared__ __align__(16) unsigned short e_lds[2][2][16 * 128];
    __shared__ unsigned short idx_lds[NN];
    __shared__ float be_lds[128];
    __shared__ int s_cnt;
    __shared__ float s_invdeg;

    const int tid  = threadIdx.x;
    const int j    = blockIdx.x;
    const int lane = tid & 63;
    const int wv   = tid >> 6;
    const int wr   = wv >> 2;
    const int wc   = wv & 3;
    const int lg   = lane >> 4;
    const int lr   = lane & 15;

    if (tid < 128) be_lds[tid] = be[tid];

    bf16x8 bwe[2];
    bf16x8 bwa[2][4];
#pragma unroll
    for (int t = 0; t < 2; ++t) {
        const int col = 32 * wc + 16 * t + lr;
        bwe[t] = *reinterpret_cast<const bf16x8*>(WeT + col * 32 + 8 * lg);
#pragma unroll
        for (int s = 0; s < 4; ++s)
            bwa[t][s] = *reinterpret_cast<const bf16x8*>(Wa2T + col * 128 + 32 * s + 8 * lg);
    }

    if (wv == 0) {
        int cnt = 0;
#pragma unroll
        for (int b = 0; b < 12; ++b) {
            float v = adjT[(size_t)j * NN + b * 64 + lane];
            unsigned long long m = __ballot(v != 0.0f);
            if (v != 0.0f) {
                int pos = cnt + __popcll(m & ((1ULL << lane) - 1ULL));
                idx_lds[pos] = (unsigned short)(b * 64 + lane);
            }
            cnt += (int)__popcll(m);
        }
        if (lane == 0) {
            s_cnt = cnt;
            s_invdeg = 1.0f / fmaxf((float)cnt, 1.0f);
        }
    }
    __syncthreads();

    const int cnt = s_cnt;
    const int Kc = (cnt + 31) >> 5;

    float aggp[2] = {0.f, 0.f};

    auto load_ef = [&](int m, float4& x0, float4& x1) {
        int s = 32 * m + 16 * wr + lr;
        int r = (s < cnt) ? (int)idx_lds[s] : 0;
        const float* p = ef + ((size_t)r * NN + j) * 32 + 8 * lg;
        x0 = *reinterpret_cast<const float4*>(p);
        x1 = *reinterpret_cast<const float4*>(p + 4);
    };
    auto gemm1 = [&](const float4& x0, const float4& x1, int buf) {
        bf16x8 a;
        a[0] = (__bf16)x0.x; a[1] = (__bf16)x0.y; a[2] = (__bf16)x0.z; a[3] = (__bf16)x0.w;
        a[4] = (__bf16)x1.x; a[5] = (__bf16)x1.y; a[6] = (__bf16)x1.z; a[7] = (__bf16)x1.w;
#pragma unroll
        for (int t = 0; t < 2; ++t) {
            const int col = 32 * wc + 16 * t + lr;
            float bb = be_lds[col];
            f32x4 c;
            c[0] = bb; c[1] = bb; c[2] = bb; c[3] = bb;
            f32x4 C1 = __builtin_amdgcn_mfma_f32_16x16x32_bf16(a, bwe[t], c, 0, 0, 0);
#pragma unroll
            for (int r = 0; r < 4; ++r) {
                int row = 4 * lg + r;
                int idx = (row * 128 + col) ^ ((row & 7) << 3);
                e_lds[buf][wr][idx] = to_bf16u(fmaxf(C1[r], 0.f));
            }
        }
    };

    float4 c0, c1;
    if (Kc > 0) {
        load_ef(0, c0, c1);
        gemm1(c0, c1, 0);
        if (Kc > 1) load_ef(1, c0, c1);
    }
    __syncthreads();

    for (int n = 0; n < Kc; ++n) {
        const int b = n & 1;
        float4 p0, p1;
        if (n + 2 < Kc) load_ef(n + 2, p0, p1);
        if (n + 1 < Kc) gemm1(c0, c1, b ^ 1);

        bf16x8 ae[4];
#pragma unroll
        for (int s = 0; s < 4; ++s) {
            int idx = (lr * 128 + 32 * s + 8 * lg) ^ ((lr & 7) << 3);
            ae[s] = *reinterpret_cast<const bf16x8*>(&e_lds[b][wr][idx]);
        }
        int srow[4];
#pragma unroll
        for (int r = 0; r < 4; ++r) {
            int s = 32 * n + 16 * wr + 4 * lg + r;
            srow[r] = (s < cnt) ? (int)idx_lds[s] : NN;
        }
#pragma unroll
        for (int t = 0; t < 2; ++t) {
            const int col = 32 * wc + 16 * t + lr;
            f32x4 acc;
#pragma unroll
            for (int r = 0; r < 4; ++r)
                acc[r] = sp[(size_t)srow[r] * 128 + col];
#pragma unroll
            for (int s = 0; s < 4; ++s)
                acc = __builtin_amdgcn_mfma_f32_16x16x32_bf16(ae[s], bwa[t][s], acc, 0, 0, 0);
#pragma unroll
            for (int r = 0; r < 4; ++r)
                aggp[t] += fmaxf(acc[r], 0.f);
        }

        if (n + 2 < Kc) { c0 = p0; c1 = p1; }
        __syncthreads();
    }

    float* red = reinterpret_cast<float*>(&e_lds[0][0][0]);
#pragma unroll
    for (int t = 0; t < 2; ++t) {
        float v = aggp[t];
        v += __shfl_xor(v, 16);
        v += __shfl_xor(v, 32);
        if (lane < 16) red[wv * 32 + 16 * t + lane] = v;
    }
    __syncthreads();
    if (tid < 128) {
        int wcol = tid >> 5, c32 = tid & 31;
        agg[(size_t)j * 128 + tid] =
            (red[wcol * 32 + c32] + red[(4 + wcol) * 32 + c32]) * s_invdeg;
    }
}

// ---------------------------------------------------------------- update (+ next-round sp, or final out)
template <int LAST>
__global__ __launch_bounds__(256) void k_upd(
                      const float* __restrict__ h_in, const float* __restrict__ agg,
                      const float* __restrict__ Wu, const float* __restrict__ bu,
                      const float* __restrict__ Wa, const float* __restrict__ ba,
                      float* __restrict__ h_out, float* __restrict__ sp,
                      float* __restrict__ out) {
    __shared__ float buf[2][256];
    __shared__ float hn[2][128];
    const int tid = threadIdx.x;
    const int row = tid >> 7, t = tid & 127;
    const int i = blockIdx.x * 2 + row;
    buf[row][t] = h_in[i * 128 + t];
    buf[row][128 + t] = agg[i * 128 + t];
    __syncthreads();
    float acc = bu[t];
#pragma unroll 8
    for (int f = 0; f < 256; ++f) acc += buf[row][f] * Wu[f * 128 + t];
    acc = fmaxf(acc, 0.f);
    if (LAST) {
        out[i * 128 + t] = acc;
    } else {
        h_out[i * 128 + t] = acc;
        hn[row][t] = acc;
        __syncthreads();
        float spv = ba[t];
#pragma unroll 8
        for (int f = 0; f < 128; ++f) spv += hn[row][f] * Wa[f * 128 + t];
        sp[i * 128 + t] = spv;
    }
}

// ---------------------------------------------------------------- graph embedding
__global__ __launch_bounds__(64) void k_gemb(const float* __restrict__ out_h, float* __restrict__ out) {
    int c = blockIdx.x, l = threadIdx.x;
    float acc = 0.f;
    for (int i = l; i < NN; i += 64) acc += out_h[(size_t)i * 128 + c];
#pragma unroll
    for (int off = 32; off; off >>= 1) acc += __shfl_down(acc, off);
    if (l == 0) out[NN * 128 + c] = acc * (1.0f / 768.0f);
}

extern "C" void kernel_launch(void* const* d_in, const int* in_sizes, int n_in,
                              void* d_out, int out_size, void* d_ws, size_t ws_size,
                              hipStream_t stream) {
    const float* nf  = (const float*)d_in[0];
    const float* ef  = (const float*)d_in[1];
    const float* adj = (const float*)d_in[2];
    const float* Wn  = (const float*)d_in[3];
    const float* bn  = (const float*)d_in[4];
    const float* We  = (const float*)d_in[5];
    const float* be  = (const float*)d_in[6];
    const float* Wa  = (const float*)d_in[7];
    const float* ba  = (const float*)d_in[8];
    const float* Wu  = (const float*)d_in[9];
    const float* bu  = (const float*)d_in[10];
    float* out = (float*)d_out;

    // workspace: h | agg | sp(+sentinel) | adjT | WeT | Wa2T | efT(bf16)
    float* h_buf = (float*)d_ws;
    float* agg   = h_buf + NN * 128;
    float* sp    = agg + NN * 128;
    float* adjT  = sp + (NN + 1) * 128;
    unsigned short* WeT  = (unsigned short*)(adjT + NN * NN);
    unsigned short* Wa2T = WeT + 128 * 32;
    unsigned short* efT  = Wa2T + 128 * 128;

    const size_t need = (size_t)(NN * 128 * 2 + (NN + 1) * 128 + NN * NN) * 4
                      + (size_t)(128 * 32 + 128 * 128) * 2
                      + (size_t)NN * NN * 32 * 2;   // 41.3 MB
    const bool use_t = ws_size >= need;

    k_prep<<<1041, 256, 0, stream>>>(adj, adjT, We, Wa, WeT, Wa2T, nf, Wn, bn, ba, h_buf, sp);

    if (use_t) {
        k_eft<<<24 * 96, 256, 0, stream>>>(ef, efT);
        k_big_t<<<NN, 512, 0, stream>>>(efT, adjT, sp, WeT, Wa2T, be, agg);
        k_upd<0><<<NN / 2, 256, 0, stream>>>(h_buf, agg, Wu, bu, Wa, ba, h_buf, sp, out);
        k_big_t<<<NN, 512, 0, stream>>>(efT, adjT, sp, WeT, Wa2T, be, agg);
        k_upd<1><<<NN / 2, 256, 0, stream>>>(h_buf, agg, Wu, bu, Wa, ba, h_buf, sp, out);
    } else {
        k_big<<<NN, 512, 0, stream>>>(ef, adjT, sp, WeT, Wa2T, be, agg);
        k_upd<0><<<NN / 2, 256, 0, stream>>>(h_buf, agg, Wu, bu, Wa, ba, h_buf, sp, out);
        k_big<<<NN, 512, 0, stream>>>(ef, adjT, sp, WeT, Wa2T, be, agg);
        k_upd<1><<<NN / 2, 256, 0, stream>>>(h_buf, agg, Wu, bu, Wa, ba, h_buf, sp, out);
    }

    k_gemb<<<128, 64, 0, stream>>>(out, out);
}

// Round 12
// 139.836 us; speedup vs baseline: 1.0441x; 1.0013x over previous
//
#include <hip/hip_runtime.h>
#include <hip/hip_bf16.h>

// GraphSAGE fused kernels for MI355X (gfx950).
// N=768, NODE_IN=64, EDGE_IN=32, H=128, ROUNDS=2.
//
// Round 12: streaming k_big_s — no compaction. R5-R11 invariant: time ==
// FETCH / ~400GB/s regardless of occupancy/registers/locality -> the
// scattered 64B gather stream is the ceiling. Pruning halved FLOPs but
// MfmaUtil is 10%: compute is cheap, scatter is expensive. Now all 768
// senders processed in order (wave loads = contiguous 1KB runs, L3-resident
// efT; sp rows sequential, L2-resident), adj mask applied as av multiply.
// Ballot/sentinel/srow machinery deleted. k_eft merged into k_prep.

typedef __bf16 bf16x8 __attribute__((ext_vector_type(8)));
typedef float f32x4 __attribute__((ext_vector_type(4)));

#define NN 768

static __device__ __forceinline__ unsigned short to_bf16u(float x) {
    return __builtin_bit_cast(unsigned short, (__bf16)x);
}

// ---------------------------------------------------------------- fused prep
// blocks 0..2303  : ef[i][j][f] fp32 -> efT[j][i][f] bf16 (LDS-tiled)
// blocks 2304..2879: adj transpose (32x32 tiles)
// blocks 2880..2959: weight transposes We->WeT, Wa[H:]->Wa2T (bf16 k-minor)
// blocks 2960..3343: h0 = relu(nf@Wn+bn) and sp = h0@Wa[:H]+ba
__global__ __launch_bounds__(256) void k_prep(
                       const float* __restrict__ ef, unsigned short* __restrict__ efT,
                       const float* __restrict__ adj, float* __restrict__ adjT,
                       const float* __restrict__ We, const float* __restrict__ Wa,
                       unsigned short* __restrict__ WeT, unsigned short* __restrict__ Wa2T,
                       const float* __restrict__ nf, const float* __restrict__ Wn,
                       const float* __restrict__ bn, const float* __restrict__ ba,
                       float* __restrict__ h, float* __restrict__ sp) {
    const int b = blockIdx.x, tid = threadIdx.x;
    if (b < 2304) {
        __shared__ unsigned short tile[8 * 1288 + 8];  // plane 1288, row 40
        const int i0 = (b % 24) * 32, j0 = (b / 24) * 8;
        {
            const int jj = tid >> 5, ff = tid & 31;
#pragma unroll 4
            for (int i = 0; i < 32; ++i) {
                float v = ef[((size_t)(i0 + i) * NN + j0 + jj) * 32 + ff];
                tile[jj * 1288 + i * 40 + ff] = to_bf16u(v);
            }
        }
        __syncthreads();
        const int tp = tid & 31, j = tid >> 5;
        unsigned short* dst = efT + ((size_t)(j0 + j) * NN + i0) * 32;
#pragma unroll
        for (int v = 0; v < 4; ++v) {
            int flat = v * 256 + tp * 8;
            int i = flat >> 5, f = flat & 31;
            bf16x8 val = *reinterpret_cast<const bf16x8*>(&tile[j * 1288 + i * 40 + f]);
            *reinterpret_cast<bf16x8*>(dst + flat) = val;
        }
    } else if (b < 2880) {
        __shared__ float tile[32][33];
        int bb = b - 2304;
        int bx = bb % 24, by = bb / 24;
        int tx = tid & 31, ty = tid >> 5;  // 32 x 8
#pragma unroll
        for (int yy = 0; yy < 32; yy += 8)
            tile[ty + yy][tx] = adj[(size_t)(by * 32 + ty + yy) * NN + bx * 32 + tx];
        __syncthreads();
#pragma unroll
        for (int yy = 0; yy < 32; yy += 8)
            adjT[(size_t)(bx * 32 + ty + yy) * NN + by * 32 + tx] = tile[tx][ty + yy];
    } else if (b < 2960) {
        int g = (b - 2880) * 256 + tid;
        if (g < 128 * 32) {
            int c = g >> 5, f = g & 31;
            WeT[g] = to_bf16u(We[f * 128 + c]);
        } else {
            int g2 = g - 128 * 32;
            int c = g2 >> 7, k = g2 & 127;
            Wa2T[g2] = to_bf16u(Wa[(128 + k) * 128 + c]);
        }
    } else {
        __shared__ float nf_l[2][64];
        __shared__ float h_l[2][128];
        int row = tid >> 7, t = tid & 127;
        int i = (b - 2960) * 2 + row;
        if (t < 64) nf_l[row][t] = nf[i * 64 + t];
        __syncthreads();
        float acc = bn[t];
#pragma unroll 8
        for (int f = 0; f < 64; ++f) acc += nf_l[row][f] * Wn[f * 128 + t];
        acc = fmaxf(acc, 0.f);
        h[i * 128 + t] = acc;
        h_l[row][t] = acc;
        __syncthreads();
        float spv = ba[t];
#pragma unroll 8
        for (int f = 0; f < 128; ++f) spv += h_l[row][f] * Wa[f * 128 + t];
        sp[i * 128 + t] = spv;
    }
}

// ---------------------------------------------------------------- streaming k_big
// Block = receiver j. 8 waves in 2x4 (wr x wc). Chunk = 32 sequential
// senders, 24 chunks, no tail. adj applied as av multiply post-relu.
__global__ __launch_bounds__(512) void k_big_s(
    const unsigned short* __restrict__ efT, const float* __restrict__ adjT,
    const float* __restrict__ sp, const unsigned short* __restrict__ WeT,
    const unsigned short* __restrict__ Wa2T, const float* __restrict__ be,
    float* __restrict__ agg) {
    __shared__ __align__(16) unsigned short e_lds[2][2][16 * 128];
    __shared__ float adj_lds[NN];
    __shared__ float be_lds[128];
    __shared__ float wred[8];
    __shared__ float s_invdeg;

    const int tid  = threadIdx.x;
    const int j    = blockIdx.x;
    const int lane = tid & 63;
    const int wv   = tid >> 6;
    const int wr   = wv >> 2;
    const int wc   = wv & 3;
    const int lg   = lane >> 4;
    const int lr   = lane & 15;

    // stage adj column j (coalesced) + degree
    float asum = 0.f;
    for (int k = tid; k < NN; k += 512) {
        float a = adjT[(size_t)j * NN + k];
        adj_lds[k] = a;
        asum += a;
    }
#pragma unroll
    for (int off = 32; off; off >>= 1) asum += __shfl_down(asum, off);
    if (lane == 0) wred[wv] = asum;
    if (tid < 128) be_lds[tid] = be[tid];

    bf16x8 bwe[2];
    bf16x8 bwa[2][4];
#pragma unroll
    for (int t = 0; t < 2; ++t) {
        const int col = 32 * wc + 16 * t + lr;
        bwe[t] = *reinterpret_cast<const bf16x8*>(WeT + col * 32 + 8 * lg);
#pragma unroll
        for (int s = 0; s < 4; ++s)
            bwa[t][s] = *reinterpret_cast<const bf16x8*>(Wa2T + col * 128 + 32 * s + 8 * lg);
    }
    __syncthreads();
    if (tid == 0) {
        float d = 0.f;
#pragma unroll
        for (int w = 0; w < 8; ++w) d += wred[w];
        s_invdeg = 1.0f / fmaxf(d, 1.0f);
    }

    float aggp[2] = {0.f, 0.f};

    // sequential streaming load: wave covers 16 consecutive rows = 1KB run
    auto load_ef = [&](int n, bf16x8& x) {
        int row = 32 * n + 16 * wr + lr;
        x = *reinterpret_cast<const bf16x8*>(efT + ((size_t)j * NN + row) * 32 + 8 * lg);
    };
    auto gemm1 = [&](bf16x8 a, int buf) {
#pragma unroll
        for (int t = 0; t < 2; ++t) {
            const int col = 32 * wc + 16 * t + lr;
            float bb = be_lds[col];
            f32x4 c;
            c[0] = bb; c[1] = bb; c[2] = bb; c[3] = bb;
            f32x4 C1 = __builtin_amdgcn_mfma_f32_16x16x32_bf16(a, bwe[t], c, 0, 0, 0);
#pragma unroll
            for (int r = 0; r < 4; ++r) {
                int row = 4 * lg + r;
                int idx = (row * 128 + col) ^ ((row & 7) << 3);
                e_lds[buf][wr][idx] = to_bf16u(fmaxf(C1[r], 0.f));
            }
        }
    };

    bf16x8 cA;
    load_ef(0, cA);
    gemm1(cA, 0);
    load_ef(1, cA);
    __syncthreads();   // E[0] ready

    for (int n = 0; n < 24; ++n) {
        const int b = n & 1;
        bf16x8 pA;
        if (n + 2 < 24) load_ef(n + 2, pA);
        if (n + 1 < 24) gemm1(cA, b ^ 1);

        bf16x8 ae[4];
#pragma unroll
        for (int s = 0; s < 4; ++s) {
            int idx = (lr * 128 + 32 * s + 8 * lg) ^ ((lr & 7) << 3);
            ae[s] = *reinterpret_cast<const bf16x8*>(&e_lds[b][wr][idx]);
        }
        const int i0 = 32 * n + 16 * wr + 4 * lg;
        f32x4 av = *reinterpret_cast<const f32x4*>(&adj_lds[i0]);
#pragma unroll
        for (int t = 0; t < 2; ++t) {
            const int col = 32 * wc + 16 * t + lr;
            f32x4 acc;
#pragma unroll
            for (int r = 0; r < 4; ++r)
                acc[r] = sp[(size_t)(i0 + r) * 128 + col];
#pragma unroll
            for (int s = 0; s < 4; ++s)
                acc = __builtin_amdgcn_mfma_f32_16x16x32_bf16(ae[s], bwa[t][s], acc, 0, 0, 0);
#pragma unroll
            for (int r = 0; r < 4; ++r)
                aggp[t] += fmaxf(acc[r], 0.f) * av[r];
        }

        if (n + 2 < 24) cA = pA;
        __syncthreads();
    }

    float* red = reinterpret_cast<float*>(&e_lds[0][0][0]);  // [8][32]
#pragma unroll
    for (int t = 0; t < 2; ++t) {
        float v = aggp[t];
        v += __shfl_xor(v, 16);
        v += __shfl_xor(v, 32);
        if (lane < 16) red[wv * 32 + 16 * t + lane] = v;
    }
    __syncthreads();
    if (tid < 128) {
        int wcol = tid >> 5, c32 = tid & 31;
        agg[(size_t)j * 128 + tid] =
            (red[wcol * 32 + c32] + red[(4 + wcol) * 32 + c32]) * s_invdeg;
    }
}

// ---------------------------------------------------------------- update (+ next-round sp, or final out)
template <int LAST>
__global__ __launch_bounds__(256) void k_upd(
                      const float* __restrict__ h_in, const float* __restrict__ agg,
                      const float* __restrict__ Wu, const float* __restrict__ bu,
                      const float* __restrict__ Wa, const float* __restrict__ ba,
                      float* __restrict__ h_out, float* __restrict__ sp,
                      float* __restrict__ out) {
    __shared__ float buf[2][256];
    __shared__ float hn[2][128];
    const int tid = threadIdx.x;
    const int row = tid >> 7, t = tid & 127;
    const int i = blockIdx.x * 2 + row;
    buf[row][t] = h_in[i * 128 + t];
    buf[row][128 + t] = agg[i * 128 + t];
    __syncthreads();
    float acc = bu[t];
#pragma unroll 8
    for (int f = 0; f < 256; ++f) acc += buf[row][f] * Wu[f * 128 + t];
    acc = fmaxf(acc, 0.f);
    if (LAST) {
        out[i * 128 + t] = acc;
    } else {
        h_out[i * 128 + t] = acc;
        hn[row][t] = acc;
        __syncthreads();
        float spv = ba[t];
#pragma unroll 8
        for (int f = 0; f < 128; ++f) spv += hn[row][f] * Wa[f * 128 + t];
        sp[i * 128 + t] = spv;
    }
}

// ---------------------------------------------------------------- graph embedding
__global__ __launch_bounds__(64) void k_gemb(const float* __restrict__ out_h, float* __restrict__ out) {
    int c = blockIdx.x, l = threadIdx.x;
    float acc = 0.f;
    for (int i = l; i < NN; i += 64) acc += out_h[(size_t)i * 128 + c];
#pragma unroll
    for (int off = 32; off; off >>= 1) acc += __shfl_down(acc, off);
    if (l == 0) out[NN * 128 + c] = acc * (1.0f / 768.0f);
}

extern "C" void kernel_launch(void* const* d_in, const int* in_sizes, int n_in,
                              void* d_out, int out_size, void* d_ws, size_t ws_size,
                              hipStream_t stream) {
    const float* nf  = (const float*)d_in[0];
    const float* ef  = (const float*)d_in[1];
    const float* adj = (const float*)d_in[2];
    const float* Wn  = (const float*)d_in[3];
    const float* bn  = (const float*)d_in[4];
    const float* We  = (const float*)d_in[5];
    const float* be  = (const float*)d_in[6];
    const float* Wa  = (const float*)d_in[7];
    const float* ba  = (const float*)d_in[8];
    const float* Wu  = (const float*)d_in[9];
    const float* bu  = (const float*)d_in[10];
    float* out = (float*)d_out;

    // workspace: h | agg | sp | adjT | WeT | Wa2T | efT(bf16)  (~41.3 MB; ws is ~302MB)
    float* h_buf = (float*)d_ws;
    float* agg   = h_buf + NN * 128;
    float* sp    = agg + NN * 128;
    float* adjT  = sp + (NN + 1) * 128;
    unsigned short* WeT  = (unsigned short*)(adjT + NN * NN);
    unsigned short* Wa2T = WeT + 128 * 32;
    unsigned short* efT  = Wa2T + 128 * 128;

    k_prep<<<3344, 256, 0, stream>>>(ef, efT, adj, adjT, We, Wa, WeT, Wa2T,
                                     nf, Wn, bn, ba, h_buf, sp);

    k_big_s<<<NN, 512, 0, stream>>>(efT, adjT, sp, WeT, Wa2T, be, agg);
    k_upd<0><<<NN / 2, 256, 0, stream>>>(h_buf, agg, Wu, bu, Wa, ba, h_buf, sp, out);
    k_big_s<<<NN, 512, 0, stream>>>(efT, adjT, sp, WeT, Wa2T, be, agg);
    k_upd<1><<<NN / 2, 256, 0, stream>>>(h_buf, agg, Wu, bu, Wa, ba, h_buf, sp, out);

    k_gemb<<<128, 64, 0, stream>>>(out, out);
}